// Round 6
// baseline (269.927 us; speedup 1.0000x reference)
//
#include <hip/hip_runtime.h>

typedef float f32x4 __attribute__((ext_vector_type(4)));

// Problem constants (from reference):
//   X:          [8][512][4096] f32
//   gates:      [8][8]          f32
//   core_first: [8][1][8][8]    f32   (E, r=1, m0, p)
//   cores_mid:  [6][8][8][8][8] f32   (i, E, r, m, p)
//   core_last:  [8][8][8][1]    f32   (E, r, n3, 1)
//   out:        [8][512][4096]  f32
//
// Math: per batch b, out[b] = (X[b] · Kin[b]) · Kout[b]  (rank-8 factorized map)
//   KinT [8][8][4096]  (b, p, m)
//   Kout [8][8][4096]  (b, p, n)

// ---------------------------------------------------------------------------
// k_compose: gate-merge the TT cores and materialize KinT / Kout. (verified)
// ---------------------------------------------------------------------------
__global__ __launch_bounds__(256) void k_compose(
    const float* __restrict__ gates,
    const float* __restrict__ core_first,
    const float* __restrict__ cores_mid,
    const float* __restrict__ core_last,
    float* __restrict__ KinT,  // [8][8][4096]
    float* __restrict__ Kout)  // [8][8][4096]
{
  const int part = blockIdx.x;   // 0..7 : m3 slice for Kin, n0 slice for Kout
  const int b    = blockIdx.y;
  const int t    = threadIdx.x;

  __shared__ float g[8];
  __shared__ float mg[3200];                     // merged cores
  __shared__ __align__(16) float A2[512];        // [(m1,m0)][p2]
  __shared__ __align__(16) float A3[512 * 9];    // [(m2,m1,m0)][p3]  stride 9
  __shared__ __align__(16) float C2[512];        // [p6][(n2,n3)]
  __shared__ __align__(16) float C3[4096];       // [p5][(n1,n2,n3)]

  if (t < 8) g[t] = gates[b*8 + t];
  __syncthreads();

  for (int idx = t; idx < 3200; idx += 256) {
    float acc = 0.f;
    if (idx < 64) {
      #pragma unroll
      for (int e = 0; e < 8; ++e) acc += g[e] * core_first[e*64 + idx];
    } else if (idx < 3136) {
      const int i = (idx - 64) >> 9;
      const int w = (idx - 64) & 511;
      #pragma unroll
      for (int e = 0; e < 8; ++e) acc += g[e] * cores_mid[(i*8 + e)*512 + w];
    } else {
      const int w = idx - 3136;
      #pragma unroll
      for (int e = 0; e < 8; ++e) acc += g[e] * core_last[e*64 + w];
    }
    mg[idx] = acc;
  }
  __syncthreads();

  const float* mg0 = mg;
  const float* mg1 = mg + 64;
  const float* mg2 = mg + 64 + 512;
  const float* mg3 = mg + 64 + 1024;
  const float* mg4 = mg + 64 + 1536;
  const float* mg5 = mg + 64 + 2048;
  const float* mg6 = mg + 64 + 2560;
  const float* mg7 = mg + 3136;

  for (int idx = t; idx < 1024; idx += 256) {
    if (idx < 512) {
      const int mm = idx >> 3, p2 = idx & 7;
      const int m1 = mm >> 3, m0 = mm & 7;
      float acc = 0.f;
      #pragma unroll
      for (int p1 = 0; p1 < 8; ++p1)
        acc += mg0[m0*8 + p1] * mg1[p1*64 + m1*8 + p2];
      A2[idx] = acc;
    } else {
      const int id = idx - 512;
      const int p6 = id >> 6, n2 = (id >> 3) & 7, n3 = id & 7;
      float acc = 0.f;
      #pragma unroll
      for (int p7 = 0; p7 < 8; ++p7)
        acc += mg6[p6*64 + n2*8 + p7] * mg7[p7*8 + n3];
      C2[id] = acc;
    }
  }
  __syncthreads();

  for (int idx = t; idx < 8192; idx += 256) {
    if (idx < 4096) {
      const int rest = idx >> 3, p3 = idx & 7;
      const int m2 = rest >> 6, mm = rest & 63;
      float acc = 0.f;
      #pragma unroll
      for (int p2 = 0; p2 < 8; ++p2)
        acc += A2[mm*8 + p2] * mg2[p2*64 + m2*8 + p3];
      A3[rest*9 + p3] = acc;
    } else {
      const int id = idx - 4096;
      const int p5 = id >> 9, n1 = (id >> 6) & 7, nn = id & 63;
      float acc = 0.f;
      #pragma unroll
      for (int p6 = 0; p6 < 8; ++p6)
        acc += mg5[p5*64 + n1*8 + p6] * C2[p6*64 + nn];
      C3[id] = acc;
    }
  }
  __syncthreads();

  {
    float* kb = KinT + b*32768;
    #pragma unroll
    for (int rr = 0; rr < 2; ++rr) {
      const int r = rr*256 + t;
      #pragma unroll
      for (int p4 = 0; p4 < 8; ++p4) {
        float acc = 0.f;
        #pragma unroll
        for (int p3 = 0; p3 < 8; ++p3)
          acc += A3[r*9 + p3] * mg3[p3*64 + part*8 + p4];
        kb[p4*4096 + part*512 + r] = acc;
      }
    }
    float* ob = Kout + b*32768 + part*512;
    #pragma unroll
    for (int jj = 0; jj < 2; ++jj) {
      const int j = jj*256 + t;
      #pragma unroll
      for (int p4 = 0; p4 < 8; ++p4) {
        float acc = 0.f;
        #pragma unroll
        for (int p5 = 0; p5 < 8; ++p5)
          acc += mg4[p4*64 + part*8 + p5] * C3[p5*512 + j];
        ob[p4*4096 + j] = acc;
      }
    }
  }
}

// ---------------------------------------------------------------------------
// k_fused v5: full-K-in-LDS + barrier-free loop + 4-DEEP X prefetch.
//   Failure ledger: R2 barriers drained vmcnt (3.3 TB/s); R3 VGPR=64, no ILP
//   (2.1); R4 reg-K spilled (3.4); R5 depth-1 prefetch + NT loads, 2 KB/wave
//   in flight (1.85).  One model fits all: outstanding-X-bytes/CU is the
//   controlling variable.
//   v5: 4-deep named-register X pipeline (8 KB/wave x 8 waves = 64 KB/CU in
//   flight >> 9 KB Little's-law need), CACHED X loads (X is L3-resident
//   across bench iterations), prologue X loads overlap the K staging.
//   Registers: acc 64 + xq 32 + temps ~20 -> ~120 < 256 cap; no spill.
// ---------------------------------------------------------------------------
__global__ __launch_bounds__(512, 2) void k_fused(
    const float* __restrict__ X,
    const float* __restrict__ KinT,
    const float* __restrict__ Kout,
    float* __restrict__ Out)
{
  const int stile = blockIdx.x;       // 0..31, 16 s-rows each
  const int b     = blockIdx.y;       // 0..7
  const int t     = threadIdx.x;      // 0..511
  const int lane  = t & 63;
  const int w     = t >> 6;           // wave id 0..7

  __shared__ __align__(16) float lk[8 * 4096];   // full KinT_b, 128 KB
  __shared__ float vs[16 * 8];                   // V tile [s_local][p]

  const int s0 = stile * 16;
  const float* xb0 = X + ((size_t)(b*512 + s0 + w*2 + 0)) * 4096 + lane*4;
  const float* xb1 = xb0 + 4096;

  // ---- Prologue X prefetch (issued BEFORE staging; in flight during it) ----
  f32x4 xq0[4], xq1[4];
  #pragma unroll
  for (int jj = 0; jj < 4; ++jj) {
    xq0[jj] = *(const f32x4*)(xb0 + jj*256);
    xq1[jj] = *(const f32x4*)(xb1 + jj*256);
  }

  // ---- Stage full K once (coalesced dwordx4, conflict-free LDS writes) ----
  {
    const f32x4* src = (const f32x4*)(KinT + (size_t)b*32768);
    f32x4*       dst = (f32x4*)lk;
    #pragma unroll
    for (int i = 0; i < 16; ++i) dst[t + i*512] = src[t + i*512];
  }
  __syncthreads();                     // ONLY barrier before the main loop

  const float* kl = lk + lane*4;

  f32x4 acc0[8], acc1[8];
  #pragma unroll
  for (int p = 0; p < 8; ++p) { acc0[p] = (f32x4)0.f; acc1[p] = (f32x4)0.f; }

  // ---- Barrier-free m-loop, 4 iterations of X in flight at all times ----
  // granule gm = j*64 + lane covers m = gm*4 .. gm*4+3
  #pragma unroll
  for (int j = 0; j < 16; ++j) {
    const f32x4 x0 = xq0[j & 3];       // loaded 4 iterations ago
    const f32x4 x1 = xq1[j & 3];
    if (j + 4 < 16) {                  // refill the slot (compile-time index)
      xq0[j & 3] = *(const f32x4*)(xb0 + (j + 4)*256);
      xq1[j & 3] = *(const f32x4*)(xb1 + (j + 4)*256);
    }
    #pragma unroll
    for (int p = 0; p < 8; ++p) {
      const f32x4 k = *(const f32x4*)(kl + p*4096 + j*256);   // ds_read_b128
      acc0[p] += x0 * k;
      acc1[p] += x1 * k;
    }
  }

  // ---- Reduce over the 64 m-granules (wave butterfly), write V tile ----
  #pragma unroll
  for (int p = 0; p < 8; ++p) {
    float s0v = acc0[p].x + acc0[p].y + acc0[p].z + acc0[p].w;
    float s1v = acc1[p].x + acc1[p].y + acc1[p].z + acc1[p].w;
    #pragma unroll
    for (int d = 1; d < 64; d <<= 1) {
      s0v += __shfl_xor(s0v, d);
      s1v += __shfl_xor(s1v, d);
    }
    if (lane == 0) {
      vs[(w*2 + 0)*8 + p] = s0v;
      vs[(w*2 + 1)*8 + p] = s1v;
    }
  }
  __syncthreads();

  // ---- Out phase: Out[b][s0+s][n] = sum_p V[s][p] * Kout[b][p][n] ----
  const float* kob = Kout + (size_t)b*32768;
  float*       ob  = Out + ((size_t)(b*512 + s0)) * 4096;

  #pragma unroll
  for (int h = 0; h < 2; ++h) {
    const int n0 = h*2048 + t*4;
    float4 kr[8];
    #pragma unroll
    for (int p = 0; p < 8; ++p)
      kr[p] = *(const float4*)(kob + p*4096 + n0);    // L2-hot, coalesced
    #pragma unroll
    for (int s = 0; s < 16; ++s) {
      const float4 va = *(const float4*)(vs + s*8);       // broadcast
      const float4 vb = *(const float4*)(vs + s*8 + 4);
      f32x4 o;
      o.x = va.x*kr[0].x + va.y*kr[1].x + va.z*kr[2].x + va.w*kr[3].x
          + vb.x*kr[4].x + vb.y*kr[5].x + vb.z*kr[6].x + vb.w*kr[7].x;
      o.y = va.x*kr[0].y + va.y*kr[1].y + va.z*kr[2].y + va.w*kr[3].y
          + vb.x*kr[4].y + vb.y*kr[5].y + vb.z*kr[6].y + vb.w*kr[7].y;
      o.z = va.x*kr[0].z + va.y*kr[1].z + va.z*kr[2].z + va.w*kr[3].z
          + vb.x*kr[4].z + vb.y*kr[5].z + vb.z*kr[6].z + vb.w*kr[7].z;
      o.w = va.x*kr[0].w + va.y*kr[1].w + va.z*kr[2].w + va.w*kr[3].w
          + vb.x*kr[4].w + vb.y*kr[5].w + vb.z*kr[6].w + vb.w*kr[7].w;
      __builtin_nontemporal_store(o, (f32x4*)(ob + (size_t)s*4096 + n0));
    }
  }
}

extern "C" void kernel_launch(void* const* d_in, const int* in_sizes, int n_in,
                              void* d_out, int out_size, void* d_ws, size_t ws_size,
                              hipStream_t stream) {
  const float* X     = (const float*)d_in[0];
  const float* gates = (const float*)d_in[1];
  const float* cf    = (const float*)d_in[2];
  const float* cm    = (const float*)d_in[3];
  const float* cl    = (const float*)d_in[4];
  float* out = (float*)d_out;

  float* ws   = (float*)d_ws;
  float* KinT = ws;                 // 262144 floats (1 MB)
  float* Kout = ws + 262144;        // 262144 floats (1 MB)

  k_compose<<<dim3(8, 8),  256, 0, stream>>>(gates, cf, cm, cl, KinT, Kout);
  k_fused <<<dim3(32, 8), 512, 0, stream>>>(X, KinT, Kout, out);
}

// Round 8
// 169.400 us; speedup vs baseline: 1.5934x; 1.5934x over previous
//
#include <hip/hip_runtime.h>

typedef float f32x4 __attribute__((ext_vector_type(4)));

#define GLOBAL_AS __attribute__((address_space(1)))
#define SHARED_AS __attribute__((address_space(3)))

// Problem constants (from reference):
//   X:          [8][512][4096] f32
//   gates:      [8][8]          f32
//   core_first: [8][1][8][8]    f32   (E, r=1, m0, p)
//   cores_mid:  [6][8][8][8][8] f32   (i, E, r, m, p)
//   core_last:  [8][8][8][1]    f32   (E, r, n3, 1)
//   out:        [8][512][4096]  f32
//
// Math: per batch b, out[b] = (X[b] · Kin[b]) · Kout[b]  (rank-8 factorized map)
//   KinT [8][8][4096]  (b, p, m)
//   Kout [8][8][4096]  (b, p, n)

// ---------------------------------------------------------------------------
// k_compose: gate-merge the TT cores and materialize KinT / Kout. (verified)
// ---------------------------------------------------------------------------
__global__ __launch_bounds__(256) void k_compose(
    const float* __restrict__ gates,
    const float* __restrict__ core_first,
    const float* __restrict__ cores_mid,
    const float* __restrict__ core_last,
    float* __restrict__ KinT,  // [8][8][4096]
    float* __restrict__ Kout)  // [8][8][4096]
{
  const int part = blockIdx.x;   // 0..7 : m3 slice for Kin, n0 slice for Kout
  const int b    = blockIdx.y;
  const int t    = threadIdx.x;

  __shared__ float g[8];
  __shared__ float mg[3200];                     // merged cores
  __shared__ __align__(16) float A2[512];        // [(m1,m0)][p2]
  __shared__ __align__(16) float A3[512 * 9];    // [(m2,m1,m0)][p3]  stride 9
  __shared__ __align__(16) float C2[512];        // [p6][(n2,n3)]
  __shared__ __align__(16) float C3[4096];       // [p5][(n1,n2,n3)]

  if (t < 8) g[t] = gates[b*8 + t];
  __syncthreads();

  for (int idx = t; idx < 3200; idx += 256) {
    float acc = 0.f;
    if (idx < 64) {
      #pragma unroll
      for (int e = 0; e < 8; ++e) acc += g[e] * core_first[e*64 + idx];
    } else if (idx < 3136) {
      const int i = (idx - 64) >> 9;
      const int w = (idx - 64) & 511;
      #pragma unroll
      for (int e = 0; e < 8; ++e) acc += g[e] * cores_mid[(i*8 + e)*512 + w];
    } else {
      const int w = idx - 3136;
      #pragma unroll
      for (int e = 0; e < 8; ++e) acc += g[e] * core_last[e*64 + w];
    }
    mg[idx] = acc;
  }
  __syncthreads();

  const float* mg0 = mg;
  const float* mg1 = mg + 64;
  const float* mg2 = mg + 64 + 512;
  const float* mg3 = mg + 64 + 1024;
  const float* mg4 = mg + 64 + 1536;
  const float* mg5 = mg + 64 + 2048;
  const float* mg6 = mg + 64 + 2560;
  const float* mg7 = mg + 3136;

  for (int idx = t; idx < 1024; idx += 256) {
    if (idx < 512) {
      const int mm = idx >> 3, p2 = idx & 7;
      const int m1 = mm >> 3, m0 = mm & 7;
      float acc = 0.f;
      #pragma unroll
      for (int p1 = 0; p1 < 8; ++p1)
        acc += mg0[m0*8 + p1] * mg1[p1*64 + m1*8 + p2];
      A2[idx] = acc;
    } else {
      const int id = idx - 512;
      const int p6 = id >> 6, n2 = (id >> 3) & 7, n3 = id & 7;
      float acc = 0.f;
      #pragma unroll
      for (int p7 = 0; p7 < 8; ++p7)
        acc += mg6[p6*64 + n2*8 + p7] * mg7[p7*8 + n3];
      C2[id] = acc;
    }
  }
  __syncthreads();

  for (int idx = t; idx < 8192; idx += 256) {
    if (idx < 4096) {
      const int rest = idx >> 3, p3 = idx & 7;
      const int m2 = rest >> 6, mm = rest & 63;
      float acc = 0.f;
      #pragma unroll
      for (int p2 = 0; p2 < 8; ++p2)
        acc += A2[mm*8 + p2] * mg2[p2*64 + m2*8 + p3];
      A3[rest*9 + p3] = acc;
    } else {
      const int id = idx - 4096;
      const int p5 = id >> 9, n1 = (id >> 6) & 7, nn = id & 63;
      float acc = 0.f;
      #pragma unroll
      for (int p6 = 0; p6 < 8; ++p6)
        acc += mg5[p5*64 + n1*8 + p6] * C2[p6*64 + nn];
      C3[id] = acc;
    }
  }
  __syncthreads();

  {
    float* kb = KinT + b*32768;
    #pragma unroll
    for (int rr = 0; rr < 2; ++rr) {
      const int r = rr*256 + t;
      #pragma unroll
      for (int p4 = 0; p4 < 8; ++p4) {
        float acc = 0.f;
        #pragma unroll
        for (int p3 = 0; p3 < 8; ++p3)
          acc += A3[r*9 + p3] * mg3[p3*64 + part*8 + p4];
        kb[p4*4096 + part*512 + r] = acc;
      }
    }
    float* ob = Kout + b*32768 + part*512;
    #pragma unroll
    for (int jj = 0; jj < 2; ++jj) {
      const int j = jj*256 + t;
      #pragma unroll
      for (int p4 = 0; p4 < 8; ++p4) {
        float acc = 0.f;
        #pragma unroll
        for (int p5 = 0; p5 < 8; ++p5)
          acc += mg4[p4*64 + part*8 + p5] * C3[p5*512 + j];
        ob[p4*4096 + j] = acc;
      }
    }
  }
}

// ---------------------------------------------------------------------------
// k_fused v7: DMA-staged (global_load_lds) X and K, zero staging VGPRs.
//   Ledger: every reg-resident X pipeline either starved (VGPR=64, R3: 2.1
//   TB/s) or spilled past the 128-VGPR toolchain cap (R4/R6: WRITE +150..225
//   MB scratch).  v7 moves ALL staging to LDS-DMA: __builtin_amdgcn_
//   global_load_lds costs no VGPRs and its completion is exactly the
//   vmcnt(0) the compiler emits before each s_barrier.
//   Block = 256 thr (4 waves) x 8 s-rows; 64 KB LDS -> 2 blocks/CU
//   (desynced barriers).  Chunked m (8 x 512), double-buffered; DMAs for
//   chunk c+1 are issued before compute of chunk c (one compute phase of
//   latency cover).  Registers: acc 64 + read temps ~40 -> ~110, no spill.
// ---------------------------------------------------------------------------
__global__ __launch_bounds__(256) void k_fused(
    const float* __restrict__ X,
    const float* __restrict__ KinT,
    const float* __restrict__ Kout,
    float* __restrict__ Out)
{
  const int stile = blockIdx.x;       // 0..63, 8 s-rows each
  const int b     = blockIdx.y;       // 0..7
  const int t     = threadIdx.x;      // 0..255
  const int lane  = t & 63;
  const int w     = t >> 6;           // wave id 0..3

  __shared__ __align__(16) float xb[2][8 * 512];   // X chunk  [row][m] 16 KB x2
  __shared__ __align__(16) float kb[2][8 * 512];   // K chunk  [p][m]   16 KB x2
  __shared__ float vs[8 * 8];                      // V tile [s_local][p]

  const int s0 = stile * 8;
  const float* xsrc = X    + ((size_t)(b*512 + s0)) * 4096;   // 8 rows
  const float* ksrc = KinT + (size_t)b*32768;

  // Stage chunk c (512 m) into buffer u.  16 X-stripes + 16 K-stripes of
  // 1 KB; wave w issues stripes {w, w+4, w+8, w+12} for each -> 8 DMA/wave.
  // LDS dst is wave-uniform; HW writes dst + lane*16.
#define STAGE(c, u) do {                                                      \
    const int coff_ = (c)*512;                                                \
    _Pragma("unroll")                                                         \
    for (int i_ = 0; i_ < 4; ++i_) {                                          \
      const int s_    = w + i_*4;          /* 0..15 */                        \
      const int row_  = s_ >> 1;           /* X row / K p   */                \
      const int half_ = (s_ & 1) * 256;                                       \
      const float* gx_ = xsrc + (size_t)row_*4096 + coff_ + half_ + lane*4;   \
      const float* gk_ = ksrc + (size_t)row_*4096 + coff_ + half_ + lane*4;   \
      __builtin_amdgcn_global_load_lds(                                       \
          (const GLOBAL_AS void*)gx_,                                         \
          (SHARED_AS void*)&xb[u][row_*512 + half_], 16, 0, 0);               \
      __builtin_amdgcn_global_load_lds(                                       \
          (const GLOBAL_AS void*)gk_,                                         \
          (SHARED_AS void*)&kb[u][row_*512 + half_], 16, 0, 0);               \
    }                                                                         \
  } while (0)

  const int r0 = w*2, r1 = w*2 + 1;     // this wave's s-rows (block-local)

  f32x4 acc0[8], acc1[8];
  #pragma unroll
  for (int p = 0; p < 8; ++p) { acc0[p] = (f32x4)0.f; acc1[p] = (f32x4)0.f; }

  STAGE(0, 0);
  __syncthreads();                      // vmcnt(0) drain == chunk 0 complete

  #pragma unroll
  for (int c = 0; c < 8; ++c) {
    const int u = c & 1;
    if (c < 7) STAGE(c + 1, u ^ 1);     // in flight during this compute phase

    #pragma unroll
    for (int g = 0; g < 2; ++g) {       // granule: m = c*512 + g*256 + lane*4
      const f32x4 x0 = *(const f32x4*)&xb[u][r0*512 + g*256 + lane*4];
      const f32x4 x1 = *(const f32x4*)&xb[u][r1*512 + g*256 + lane*4];
      #pragma unroll
      for (int p = 0; p < 8; ++p) {
        const f32x4 k = *(const f32x4*)&kb[u][p*512 + g*256 + lane*4];
        acc0[p] += x0 * k;
        acc1[p] += x1 * k;
      }
    }
    __syncthreads();                    // drains DMAs (next buf ready), frees cur
  }
#undef STAGE

  // ---- Reduce over the 64 m-granules (wave butterfly), write V tile ----
  #pragma unroll
  for (int p = 0; p < 8; ++p) {
    float s0v = acc0[p].x + acc0[p].y + acc0[p].z + acc0[p].w;
    float s1v = acc1[p].x + acc1[p].y + acc1[p].z + acc1[p].w;
    #pragma unroll
    for (int d = 1; d < 64; d <<= 1) {
      s0v += __shfl_xor(s0v, d);
      s1v += __shfl_xor(s1v, d);
    }
    if (lane == 0) {
      vs[r0*8 + p] = s0v;
      vs[r1*8 + p] = s1v;
    }
  }
  __syncthreads();

  // ---- Out phase (verified R2 epilogue): Out[b][s0+s][:] = V[s]·Kout[b] ----
  float4 vA[8], vB[8];
  #pragma unroll
  for (int s = 0; s < 8; ++s) {
    vA[s] = *(const float4*)(vs + s*8);       // p 0..3 (broadcast)
    vB[s] = *(const float4*)(vs + s*8 + 4);   // p 4..7
  }

  const float* kob = Kout + (size_t)b*32768 + t*4;
  float*       ob  = Out + ((size_t)(b*512 + s0))*4096 + t*4;

  #pragma unroll
  for (int nc = 0; nc < 4; ++nc) {
    float4 kr[8];
    #pragma unroll
    for (int p = 0; p < 8; ++p)
      kr[p] = *(const float4*)(kob + p*4096 + nc*1024);   // L2-hot, coalesced
    #pragma unroll
    for (int s = 0; s < 8; ++s) {
      f32x4 o;
      o.x = vA[s].x*kr[0].x + vA[s].y*kr[1].x + vA[s].z*kr[2].x + vA[s].w*kr[3].x
          + vB[s].x*kr[4].x + vB[s].y*kr[5].x + vB[s].z*kr[6].x + vB[s].w*kr[7].x;
      o.y = vA[s].x*kr[0].y + vA[s].y*kr[1].y + vA[s].z*kr[2].y + vA[s].w*kr[3].y
          + vB[s].x*kr[4].y + vB[s].y*kr[5].y + vB[s].z*kr[6].y + vB[s].w*kr[7].y;
      o.z = vA[s].x*kr[0].z + vA[s].y*kr[1].z + vA[s].z*kr[2].z + vA[s].w*kr[3].z
          + vB[s].x*kr[4].z + vB[s].y*kr[5].z + vB[s].z*kr[6].z + vB[s].w*kr[7].z;
      o.w = vA[s].x*kr[0].w + vA[s].y*kr[1].w + vA[s].z*kr[2].w + vA[s].w*kr[3].w
          + vB[s].x*kr[4].w + vB[s].y*kr[5].w + vB[s].z*kr[6].w + vB[s].w*kr[7].w;
      __builtin_nontemporal_store(o, (f32x4*)(ob + (size_t)s*4096 + nc*1024));
    }
  }
}

extern "C" void kernel_launch(void* const* d_in, const int* in_sizes, int n_in,
                              void* d_out, int out_size, void* d_ws, size_t ws_size,
                              hipStream_t stream) {
  const float* X     = (const float*)d_in[0];
  const float* gates = (const float*)d_in[1];
  const float* cf    = (const float*)d_in[2];
  const float* cm    = (const float*)d_in[3];
  const float* cl    = (const float*)d_in[4];
  float* out = (float*)d_out;

  float* ws   = (float*)d_ws;
  float* KinT = ws;                 // 262144 floats (1 MB)
  float* Kout = ws + 262144;        // 262144 floats (1 MB)

  k_compose<<<dim3(8, 8),  256, 0, stream>>>(gates, cf, cm, cl, KinT, Kout);
  k_fused <<<dim3(64, 8), 256, 0, stream>>>(X, KinT, Kout, out);
}

// Round 9
// 159.779 us; speedup vs baseline: 1.6894x; 1.0602x over previous
//
#include <hip/hip_runtime.h>

typedef float f32x4 __attribute__((ext_vector_type(4)));

#define GLOBAL_AS __attribute__((address_space(1)))
#define SHARED_AS __attribute__((address_space(3)))

// Problem constants (from reference):
//   X:          [8][512][4096] f32
//   gates:      [8][8]          f32
//   core_first: [8][1][8][8]    f32   (E, r=1, m0, p)
//   cores_mid:  [6][8][8][8][8] f32   (i, E, r, m, p)
//   core_last:  [8][8][8][1]    f32   (E, r, n3, 1)
//   out:        [8][512][4096]  f32
//
// Math: per batch b, out[b] = (X[b] · Kin[b]) · Kout[b]  (rank-8 factorized map)
//   KinT [8][8][4096]  (b, p, m)
//   Kout [8][8][4096]  (b, p, n)

// ---------------------------------------------------------------------------
// k_compose v2: split dataflow for parallelism.
//   Old: 64 blocks, 5 serial LDS-chained phases (~50 us by time-ledger).
//   New: grid (8 part, 8 b, 8 z).  z<4: Kin pipeline only, m2-pair {2z,2z+1};
//   z>=4: Kout pipeline only, n1-pair.  512 blocks, ~4x less serial depth per
//   block, arithmetic identical to the verified R2 version.
// ---------------------------------------------------------------------------
__global__ __launch_bounds__(256) void k_compose(
    const float* __restrict__ gates,
    const float* __restrict__ core_first,
    const float* __restrict__ cores_mid,
    const float* __restrict__ core_last,
    float* __restrict__ KinT,  // [8][8][4096]
    float* __restrict__ Kout)  // [8][8][4096]
{
  const int part = blockIdx.x;   // 0..7 : m3 for Kin, n0 for Kout
  const int b    = blockIdx.y;   // 0..7
  const int z    = blockIdx.z;   // 0..3 Kin m2-pair, 4..7 Kout n1-pair
  const int t    = threadIdx.x;

  __shared__ float g[8];
  __shared__ float mg[1600];                    // 4 merged cores for this path
  __shared__ __align__(16) float S1[512];       // A2 or C2
  __shared__ __align__(16) float S2[128 * 9];   // A3 slice (pad 9) or C3 slice

  if (t < 8) g[t] = gates[b*8 + t];
  __syncthreads();

  if (z < 4) {
    // ================= Kin path: mg0(cf) mg1(i0) mg2(i1) mg3(i2) ==========
    // layout: mg0 @0(64), mg1 @64, mg2 @576, mg3 @1088
    for (int idx = t; idx < 1600; idx += 256) {
      float acc = 0.f;
      if (idx < 64) {
        #pragma unroll
        for (int e = 0; e < 8; ++e) acc += g[e] * core_first[e*64 + idx];
      } else {
        const int i = (idx - 64) >> 9;          // 0,1,2
        const int w2 = (idx - 64) & 511;
        #pragma unroll
        for (int e = 0; e < 8; ++e) acc += g[e] * cores_mid[(i*8 + e)*512 + w2];
      }
      mg[idx] = acc;
    }
    __syncthreads();

    // A2[(m1,m0)][p2], full 512
    #pragma unroll
    for (int i = 0; i < 2; ++i) {
      const int idx = i*256 + t;
      const int mm = idx >> 3, p2 = idx & 7;
      const int m1 = mm >> 3, m0 = mm & 7;
      float acc = 0.f;
      #pragma unroll
      for (int p1 = 0; p1 < 8; ++p1)
        acc += mg[m0*8 + p1] * mg[64 + p1*64 + m1*8 + p2];
      S1[idx] = acc;
    }
    __syncthreads();

    // A3 slice: rl in [0,128) over m2 = 2z + (rl>>6), mm = rl&63
    #pragma unroll
    for (int i = 0; i < 4; ++i) {
      const int idx = i*256 + t;
      const int rl = idx >> 3, p3 = idx & 7;
      const int m2 = 2*z + (rl >> 6), mm = rl & 63;
      float acc = 0.f;
      #pragma unroll
      for (int p2 = 0; p2 < 8; ++p2)
        acc += S1[mm*8 + p2] * mg[576 + p2*64 + m2*8 + p3];
      S2[rl*9 + p3] = acc;
    }
    __syncthreads();

    // Kin write: r_global = z*128 + rl
    float* kb = KinT + b*32768;
    #pragma unroll
    for (int i = 0; i < 4; ++i) {
      const int idx = i*256 + t;
      const int rl = idx >> 3, p4 = idx & 7;
      float acc = 0.f;
      #pragma unroll
      for (int p3 = 0; p3 < 8; ++p3)
        acc += S2[rl*9 + p3] * mg[1088 + p3*64 + part*8 + p4];
      kb[p4*4096 + part*512 + z*128 + rl] = acc;
    }
  } else {
    // ================= Kout path: mg4(i3) mg5(i4) mg6(i5) mg7(cl) =========
    // layout: mg4 @0, mg5 @512, mg6 @1024, mg7 @1536(64)
    const int zz = z - 4;
    for (int idx = t; idx < 1600; idx += 256) {
      float acc = 0.f;
      if (idx < 1536) {
        const int i = 3 + (idx >> 9);           // 3,4,5
        const int w2 = idx & 511;
        #pragma unroll
        for (int e = 0; e < 8; ++e) acc += g[e] * cores_mid[(i*8 + e)*512 + w2];
      } else {
        const int w2 = idx - 1536;
        #pragma unroll
        for (int e = 0; e < 8; ++e) acc += g[e] * core_last[e*64 + w2];
      }
      mg[idx] = acc;
    }
    __syncthreads();

    // C2[p6][(n2,n3)], full 512
    #pragma unroll
    for (int i = 0; i < 2; ++i) {
      const int id = i*256 + t;
      const int p6 = id >> 6, n2 = (id >> 3) & 7, n3 = id & 7;
      float acc = 0.f;
      #pragma unroll
      for (int p7 = 0; p7 < 8; ++p7)
        acc += mg[1024 + p6*64 + n2*8 + p7] * mg[1536 + p7*8 + n3];
      S1[id] = acc;
    }
    __syncthreads();

    // C3 slice: [p5][jl], jl in [0,128) over n1 = 2zz + (jl>>6), nn = jl&63
    #pragma unroll
    for (int i = 0; i < 4; ++i) {
      const int idx = i*256 + t;
      const int p5 = idx >> 7, jl = idx & 127;
      const int n1 = 2*zz + (jl >> 6), nn = jl & 63;
      float acc = 0.f;
      #pragma unroll
      for (int p6 = 0; p6 < 8; ++p6)
        acc += mg[512 + p5*64 + n1*8 + p6] * S1[p6*64 + nn];
      S2[p5*128 + jl] = acc;
    }
    __syncthreads();

    // Kout write: j = zz*128 + jl
    float* ob = Kout + b*32768 + part*512 + zz*128;
    #pragma unroll
    for (int i = 0; i < 4; ++i) {
      const int idx = i*256 + t;
      const int jl = idx >> 3, p4 = idx & 7;
      float acc = 0.f;
      #pragma unroll
      for (int p5 = 0; p5 < 8; ++p5)
        acc += mg[p4*64 + part*8 + p5] * S2[p5*128 + jl];
      ob[p4*4096 + jl] = acc;
    }
  }
}

// ---------------------------------------------------------------------------
// k_fused v8: DMA staging + COUNTED vmcnt pipeline (T3/T4), 4-deep buffers.
//   R8 worked (FETCH clean, 0 conflicts) but __syncthreads' vmcnt(0) drained
//   the just-issued next-chunk DMAs every iteration -> one-compute-phase
//   latency cover vs ~900cy HBM latency.  v8: 16 chunks x 256 m, 4 buffers,
//   raw s_barrier with s_waitcnt vmcnt(8): two chunks of DMAs stay in flight
//   across barriers (guide T4: never drain to 0 in the main loop).
//   Per wave per STAGE: 4 DMAs (X rows {w,w+4}, K rows {w,w+4}), so
//   vmcnt(8) == "current chunk complete, 2 look-ahead chunks outstanding".
// ---------------------------------------------------------------------------
__global__ __launch_bounds__(256) void k_fused(
    const float* __restrict__ X,
    const float* __restrict__ KinT,
    const float* __restrict__ Kout,
    float* __restrict__ Out)
{
  const int stile = blockIdx.x;       // 0..63, 8 s-rows each
  const int b     = blockIdx.y;       // 0..7
  const int t     = threadIdx.x;      // 0..255
  const int lane  = t & 63;
  const int w     = t >> 6;           // wave id 0..3

  __shared__ __align__(16) float xs[4][8 * 256];   // X chunk bufs, 8 KB each
  __shared__ __align__(16) float ks[4][8 * 256];   // K chunk bufs, 8 KB each
  __shared__ float vs[8 * 8];                      // V tile [s_local][p]

  const int s0 = stile * 8;
  const float* xsrc = X    + ((size_t)(b*512 + s0)) * 4096;   // 8 rows
  const float* ksrc = KinT + (size_t)b*32768;

  // Wave w stages X rows {w, w+4} and K rows {w, w+4}: 4 DMAs x 1 KB.
#define STAGE(c, u) do {                                                       \
    const int off_ = (c)*256 + lane*4;                                         \
    __builtin_amdgcn_global_load_lds(                                          \
        (const GLOBAL_AS void*)(xsrc + (size_t)(w)*4096 + off_),               \
        (SHARED_AS void*)&xs[u][(w)*256], 16, 0, 0);                           \
    __builtin_amdgcn_global_load_lds(                                          \
        (const GLOBAL_AS void*)(xsrc + (size_t)(w + 4)*4096 + off_),           \
        (SHARED_AS void*)&xs[u][(w + 4)*256], 16, 0, 0);                       \
    __builtin_amdgcn_global_load_lds(                                          \
        (const GLOBAL_AS void*)(ksrc + (size_t)(w)*4096 + off_),               \
        (SHARED_AS void*)&ks[u][(w)*256], 16, 0, 0);                           \
    __builtin_amdgcn_global_load_lds(                                          \
        (const GLOBAL_AS void*)(ksrc + (size_t)(w + 4)*4096 + off_),           \
        (SHARED_AS void*)&ks[u][(w + 4)*256], 16, 0, 0);                       \
  } while (0)

  const int r0 = w*2, r1 = w*2 + 1;   // this wave's s-rows (block-local)

  f32x4 acc0[8], acc1[8];
  #pragma unroll
  for (int p = 0; p < 8; ++p) { acc0[p] = (f32x4)0.f; acc1[p] = (f32x4)0.f; }

  // Prologue: 3 chunks in flight (12 DMAs/wave).
  STAGE(0, 0);
  STAGE(1, 1);
  STAGE(2, 2);

  #pragma unroll
  for (int c = 0; c < 16; ++c) {
    // Counted wait: chunk c's 4 DMAs done; look-ahead stays outstanding.
    if (c <= 13)      asm volatile("s_waitcnt vmcnt(8)" ::: "memory");
    else if (c == 14) asm volatile("s_waitcnt vmcnt(4)" ::: "memory");
    else              asm volatile("s_waitcnt vmcnt(0)" ::: "memory");
    __builtin_amdgcn_s_barrier();       // all waves certify chunk c staged;
                                        // also: everyone passed compute(c-1),
                                        // so buf (c+3)&3 is safe to overwrite
    if (c + 3 < 16) STAGE(c + 3, (c + 3) & 3);

    const int u = c & 3;
    const f32x4 x0 = *(const f32x4*)&xs[u][r0*256 + lane*4];
    const f32x4 x1 = *(const f32x4*)&xs[u][r1*256 + lane*4];
    #pragma unroll
    for (int p = 0; p < 8; ++p) {
      const f32x4 k = *(const f32x4*)&ks[u][p*256 + lane*4];
      acc0[p] += x0 * k;
      acc1[p] += x1 * k;
    }
  }
#undef STAGE

  // ---- Reduce over the 64 m-granules (wave butterfly), write V tile ----
  #pragma unroll
  for (int p = 0; p < 8; ++p) {
    float s0v = acc0[p].x + acc0[p].y + acc0[p].z + acc0[p].w;
    float s1v = acc1[p].x + acc1[p].y + acc1[p].z + acc1[p].w;
    #pragma unroll
    for (int d = 1; d < 64; d <<= 1) {
      s0v += __shfl_xor(s0v, d);
      s1v += __shfl_xor(s1v, d);
    }
    if (lane == 0) {
      vs[r0*8 + p] = s0v;
      vs[r1*8 + p] = s1v;
    }
  }
  __syncthreads();

  // ---- Out phase (verified epilogue): Out[b][s0+s][:] = V[s]·Kout[b] ----
  float4 vA[8], vB[8];
  #pragma unroll
  for (int s = 0; s < 8; ++s) {
    vA[s] = *(const float4*)(vs + s*8);       // p 0..3 (broadcast)
    vB[s] = *(const float4*)(vs + s*8 + 4);   // p 4..7
  }

  const float* kob = Kout + (size_t)b*32768 + t*4;
  float*       ob  = Out + ((size_t)(b*512 + s0))*4096 + t*4;

  #pragma unroll
  for (int nc = 0; nc < 4; ++nc) {
    float4 kr[8];
    #pragma unroll
    for (int p = 0; p < 8; ++p)
      kr[p] = *(const float4*)(kob + p*4096 + nc*1024);   // L2-hot, coalesced
    #pragma unroll
    for (int s = 0; s < 8; ++s) {
      f32x4 o;
      o.x = vA[s].x*kr[0].x + vA[s].y*kr[1].x + vA[s].z*kr[2].x + vA[s].w*kr[3].x
          + vB[s].x*kr[4].x + vB[s].y*kr[5].x + vB[s].z*kr[6].x + vB[s].w*kr[7].x;
      o.y = vA[s].x*kr[0].y + vA[s].y*kr[1].y + vA[s].z*kr[2].y + vA[s].w*kr[3].y
          + vB[s].x*kr[4].y + vB[s].y*kr[5].y + vB[s].z*kr[6].y + vB[s].w*kr[7].y;
      o.z = vA[s].x*kr[0].z + vA[s].y*kr[1].z + vA[s].z*kr[2].z + vA[s].w*kr[3].z
          + vB[s].x*kr[4].z + vB[s].y*kr[5].z + vB[s].z*kr[6].z + vB[s].w*kr[7].z;
      o.w = vA[s].x*kr[0].w + vA[s].y*kr[1].w + vA[s].z*kr[2].w + vA[s].w*kr[3].w
          + vB[s].x*kr[4].w + vB[s].y*kr[5].w + vB[s].z*kr[6].w + vB[s].w*kr[7].w;
      __builtin_nontemporal_store(o, (f32x4*)(ob + (size_t)s*4096 + nc*1024));
    }
  }
}

extern "C" void kernel_launch(void* const* d_in, const int* in_sizes, int n_in,
                              void* d_out, int out_size, void* d_ws, size_t ws_size,
                              hipStream_t stream) {
  const float* X     = (const float*)d_in[0];
  const float* gates = (const float*)d_in[1];
  const float* cf    = (const float*)d_in[2];
  const float* cm    = (const float*)d_in[3];
  const float* cl    = (const float*)d_in[4];
  float* out = (float*)d_out;

  float* ws   = (float*)d_ws;
  float* KinT = ws;                 // 262144 floats (1 MB)
  float* Kout = ws + 262144;        // 262144 floats (1 MB)

  k_compose<<<dim3(8, 8, 8), 256, 0, stream>>>(gates, cf, cm, cl, KinT, Kout);
  k_fused  <<<dim3(64, 8),   256, 0, stream>>>(X, KinT, Kout, out);
}

// Round 11
// 155.439 us; speedup vs baseline: 1.7366x; 1.0279x over previous
//
#include <hip/hip_runtime.h>

typedef float f32x4 __attribute__((ext_vector_type(4)));

// Problem constants (from reference):
//   X:          [8][512][4096] f32
//   gates:      [8][8]          f32
//   core_first: [8][1][8][8]    f32   (E, r=1, m0, p)
//   cores_mid:  [6][8][8][8][8] f32   (i, E, r, m, p)
//   core_last:  [8][8][8][1]    f32   (E, r, n3, 1)
//   out:        [8][512][4096]  f32
//
// Math: per batch b, out[b] = (X[b] · Kin[b]) · Kout[b]  (rank-8 factorized map)
//   KinT [8][8][4096]  (b, p, m)
//   Kout [8][8][4096]  (b, p, n)

// ---------------------------------------------------------------------------
// k_compose v2 (verified R9): split dataflow, grid (8 part, 8 b, 8 z).
// ---------------------------------------------------------------------------
__global__ __launch_bounds__(256) void k_compose(
    const float* __restrict__ gates,
    const float* __restrict__ core_first,
    const float* __restrict__ cores_mid,
    const float* __restrict__ core_last,
    float* __restrict__ KinT,  // [8][8][4096]
    float* __restrict__ Kout)  // [8][8][4096]
{
  const int part = blockIdx.x;   // 0..7 : m3 for Kin, n0 for Kout
  const int b    = blockIdx.y;   // 0..7
  const int z    = blockIdx.z;   // 0..3 Kin m2-pair, 4..7 Kout n1-pair
  const int t    = threadIdx.x;

  __shared__ float g[8];
  __shared__ float mg[1600];                    // 4 merged cores for this path
  __shared__ __align__(16) float S1[512];       // A2 or C2
  __shared__ __align__(16) float S2[128 * 9];   // A3 slice (pad 9) or C3 slice

  if (t < 8) g[t] = gates[b*8 + t];
  __syncthreads();

  if (z < 4) {
    // ---- Kin path: mg0(cf)@0, mg1(i0)@64, mg2(i1)@576, mg3(i2)@1088 ----
    for (int idx = t; idx < 1600; idx += 256) {
      float acc = 0.f;
      if (idx < 64) {
        #pragma unroll
        for (int e = 0; e < 8; ++e) acc += g[e] * core_first[e*64 + idx];
      } else {
        const int i = (idx - 64) >> 9;          // 0,1,2
        const int w2 = (idx - 64) & 511;
        #pragma unroll
        for (int e = 0; e < 8; ++e) acc += g[e] * cores_mid[(i*8 + e)*512 + w2];
      }
      mg[idx] = acc;
    }
    __syncthreads();

    #pragma unroll
    for (int i = 0; i < 2; ++i) {
      const int idx = i*256 + t;
      const int mm = idx >> 3, p2 = idx & 7;
      const int m1 = mm >> 3, m0 = mm & 7;
      float acc = 0.f;
      #pragma unroll
      for (int p1 = 0; p1 < 8; ++p1)
        acc += mg[m0*8 + p1] * mg[64 + p1*64 + m1*8 + p2];
      S1[idx] = acc;
    }
    __syncthreads();

    #pragma unroll
    for (int i = 0; i < 4; ++i) {
      const int idx = i*256 + t;
      const int rl = idx >> 3, p3 = idx & 7;
      const int m2 = 2*z + (rl >> 6), mm = rl & 63;
      float acc = 0.f;
      #pragma unroll
      for (int p2 = 0; p2 < 8; ++p2)
        acc += S1[mm*8 + p2] * mg[576 + p2*64 + m2*8 + p3];
      S2[rl*9 + p3] = acc;
    }
    __syncthreads();

    float* kb = KinT + b*32768;
    #pragma unroll
    for (int i = 0; i < 4; ++i) {
      const int idx = i*256 + t;
      const int rl = idx >> 3, p4 = idx & 7;
      float acc = 0.f;
      #pragma unroll
      for (int p3 = 0; p3 < 8; ++p3)
        acc += S2[rl*9 + p3] * mg[1088 + p3*64 + part*8 + p4];
      kb[p4*4096 + part*512 + z*128 + rl] = acc;
    }
  } else {
    // ---- Kout path: mg4(i3)@0, mg5(i4)@512, mg6(i5)@1024, mg7(cl)@1536 ----
    const int zz = z - 4;
    for (int idx = t; idx < 1600; idx += 256) {
      float acc = 0.f;
      if (idx < 1536) {
        const int i = 3 + (idx >> 9);           // 3,4,5
        const int w2 = idx & 511;
        #pragma unroll
        for (int e = 0; e < 8; ++e) acc += g[e] * cores_mid[(i*8 + e)*512 + w2];
      } else {
        const int w2 = idx - 1536;
        #pragma unroll
        for (int e = 0; e < 8; ++e) acc += g[e] * core_last[e*64 + w2];
      }
      mg[idx] = acc;
    }
    __syncthreads();

    #pragma unroll
    for (int i = 0; i < 2; ++i) {
      const int id = i*256 + t;
      const int p6 = id >> 6, n2 = (id >> 3) & 7, n3 = id & 7;
      float acc = 0.f;
      #pragma unroll
      for (int p7 = 0; p7 < 8; ++p7)
        acc += mg[1024 + p6*64 + n2*8 + p7] * mg[1536 + p7*8 + n3];
      S1[id] = acc;
    }
    __syncthreads();

    #pragma unroll
    for (int i = 0; i < 4; ++i) {
      const int idx = i*256 + t;
      const int p5 = idx >> 7, jl = idx & 127;
      const int n1 = 2*zz + (jl >> 6), nn = jl & 63;
      float acc = 0.f;
      #pragma unroll
      for (int p6 = 0; p6 < 8; ++p6)
        acc += mg[512 + p5*64 + n1*8 + p6] * S1[p6*64 + nn];
      S2[p5*128 + jl] = acc;
    }
    __syncthreads();

    float* ob = Kout + b*32768 + part*512 + zz*128;
    #pragma unroll
    for (int i = 0; i < 4; ++i) {
      const int idx = i*256 + t;
      const int jl = idx >> 3, p4 = idx & 7;
      float acc = 0.f;
      #pragma unroll
      for (int p5 = 0; p5 < 8; ++p5)
        acc += mg[p4*64 + part*8 + p5] * S2[p5*128 + jl];
      ob[p4*4096 + jl] = acc;
    }
  }
}

// ---------------------------------------------------------------------------
// k_fused v9: NO LDS staging, NO main-loop barriers, NO DMA.  TLP does the
//   latency hiding.
//   R8/R9 post-mortem: counted vmcnt was NULL (62.6 -> 62.5 us) => the wait
//   schedule wasn't the constraint.  Arithmetic: 512 global_load_lds per CU
//   over 150K cycles = ~293 cyc/DMA serialized -- and m97's GEMM shows the
//   same ~370 cyc/DMA rate.  global_load_lds has a ~1KB/300cyc/CU throughput
//   ceiling (~2.5 TB/s chip) -- the exact plateau of every staged variant.
//   v9: one wave = one s-row (acc = 32 VGPR only); X and K read straight
//   through the caches (K is 2 MB, L2-resident); 9 independent loads per
//   j-iter.  Grid 1024 blocks = 4 blocks/CU = 16 waves/CU: TLP supplies
//   32-64 KB in flight per CU >> 9.2 KB Little's-law requirement.
// ---------------------------------------------------------------------------
__global__ __launch_bounds__(256) void k_fused(
    const float* __restrict__ X,
    const float* __restrict__ KinT,
    const float* __restrict__ Kout,
    float* __restrict__ Out)
{
  const int stile = blockIdx.x;       // 0..127, 4 s-rows each
  const int b     = blockIdx.y;       // 0..7
  const int t     = threadIdx.x;      // 0..255
  const int lane  = t & 63;
  const int w     = t >> 6;           // wave id 0..3 == local s-row

  __shared__ float vs[4 * 8];         // V tile [s_local][p]

  const int s = stile*4 + w;
  const float* xrow = X    + ((size_t)(b*512 + s))*4096 + lane*4;
  const float* kb   = KinT + (size_t)b*32768 + lane*4;

  f32x4 acc[8];
  #pragma unroll
  for (int p = 0; p < 8; ++p) acc[p] = (f32x4)0.f;

  // m-loop: granule gm = j*64 + lane covers m = gm*4 .. gm*4+3.
  // 9 independent loads per j (1 X from HBM/L3, 8 K from L2) -> intra-wave
  // ILP; 16 waves/CU -> inter-wave TLP.  No barriers anywhere in this loop.
  #pragma unroll
  for (int j = 0; j < 16; ++j) {
    const f32x4 x  = *(const f32x4*)(xrow + j*256);
    const f32x4 k0 = *(const f32x4*)(kb + 0*4096 + j*256);
    const f32x4 k1 = *(const f32x4*)(kb + 1*4096 + j*256);
    const f32x4 k2 = *(const f32x4*)(kb + 2*4096 + j*256);
    const f32x4 k3 = *(const f32x4*)(kb + 3*4096 + j*256);
    const f32x4 k4 = *(const f32x4*)(kb + 4*4096 + j*256);
    const f32x4 k5 = *(const f32x4*)(kb + 5*4096 + j*256);
    const f32x4 k6 = *(const f32x4*)(kb + 6*4096 + j*256);
    const f32x4 k7 = *(const f32x4*)(kb + 7*4096 + j*256);
    acc[0] += x * k0;  acc[1] += x * k1;
    acc[2] += x * k2;  acc[3] += x * k3;
    acc[4] += x * k4;  acc[5] += x * k5;
    acc[6] += x * k6;  acc[7] += x * k7;
  }

  // ---- Reduce over the 64 m-granules (wave butterfly), write V tile ----
  #pragma unroll
  for (int p = 0; p < 8; ++p) {
    float v = acc[p].x + acc[p].y + acc[p].z + acc[p].w;
    #pragma unroll
    for (int d = 1; d < 64; d <<= 1) v += __shfl_xor(v, d);
    if (lane == 0) vs[w*8 + p] = v;
  }
  __syncthreads();

  // ---- Out phase (verified epilogue): Out[b][stile*4+s][:] = V[s]·Kout[b] ----
  float4 vA[4], vB[4];
  #pragma unroll
  for (int sl = 0; sl < 4; ++sl) {
    vA[sl] = *(const float4*)(vs + sl*8);       // p 0..3 (broadcast)
    vB[sl] = *(const float4*)(vs + sl*8 + 4);   // p 4..7
  }

  const float* kob = Kout + (size_t)b*32768 + t*4;
  float*       ob  = Out + ((size_t)(b*512 + stile*4))*4096 + t*4;

  #pragma unroll
  for (int nc = 0; nc < 4; ++nc) {
    float4 kr[8];
    #pragma unroll
    for (int p = 0; p < 8; ++p)
      kr[p] = *(const float4*)(kob + p*4096 + nc*1024);   // L2-hot, coalesced
    #pragma unroll
    for (int sl = 0; sl < 4; ++sl) {
      f32x4 o;
      o.x = vA[sl].x*kr[0].x + vA[sl].y*kr[1].x + vA[sl].z*kr[2].x + vA[sl].w*kr[3].x
          + vB[sl].x*kr[4].x + vB[sl].y*kr[5].x + vB[sl].z*kr[6].x + vB[sl].w*kr[7].x;
      o.y = vA[sl].x*kr[0].y + vA[sl].y*kr[1].y + vA[sl].z*kr[2].y + vA[sl].w*kr[3].y
          + vB[sl].x*kr[4].y + vB[sl].y*kr[5].y + vB[sl].z*kr[6].y + vB[sl].w*kr[7].y;
      o.z = vA[sl].x*kr[0].z + vA[sl].y*kr[1].z + vA[sl].z*kr[2].z + vA[sl].w*kr[3].z
          + vB[sl].x*kr[4].z + vB[sl].y*kr[5].z + vB[sl].z*kr[6].z + vB[sl].w*kr[7].z;
      o.w = vA[sl].x*kr[0].w + vA[sl].y*kr[1].w + vA[sl].z*kr[2].w + vA[sl].w*kr[3].w
          + vB[sl].x*kr[4].w + vB[sl].y*kr[5].w + vB[sl].z*kr[6].w + vB[sl].w*kr[7].w;
      __builtin_nontemporal_store(o, (f32x4*)(ob + (size_t)sl*4096 + nc*1024));
    }
  }
}

extern "C" void kernel_launch(void* const* d_in, const int* in_sizes, int n_in,
                              void* d_out, int out_size, void* d_ws, size_t ws_size,
                              hipStream_t stream) {
  const float* X     = (const float*)d_in[0];
  const float* gates = (const float*)d_in[1];
  const float* cf    = (const float*)d_in[2];
  const float* cm    = (const float*)d_in[3];
  const float* cl    = (const float*)d_in[4];
  float* out = (float*)d_out;

  float* ws   = (float*)d_ws;
  float* KinT = ws;                 // 262144 floats (1 MB)
  float* Kout = ws + 262144;        // 262144 floats (1 MB)

  k_compose<<<dim3(8, 8, 8), 256, 0, stream>>>(gates, cf, cm, cl, KinT, Kout);
  k_fused  <<<dim3(128, 8),  256, 0, stream>>>(X, KinT, Kout, out);
}